// Round 10
// baseline (1006.001 us; speedup 1.0000x reference)
//
#include <hip/hip_runtime.h>
#include <hip/hip_cooperative_groups.h>

namespace cg = cooperative_groups;

#define N_NODES 50000
#define N_EDGES 800000
#define DIM 128
#define N_REL 86
#define BATCH 2048

#define TPAD 136              // 128+8 bf16: 272 B row stride -> 2-way bank alias (free)
#define QPAD 136

#define G_CNT  782            // ceil(800000/1024), 4 edges/thread
#define G_GEMM 391            // ceil(50000/128)
#define G_TQ   172            // 86 relations x 2 d-blocks
#define NB_SCAN 49            // ceil(50000/1024)
#define G_AGG  6250           // 50000/8
#define G_PRED (16 * N_REL)   // 16 batch-tiles x 86 relations

using bf16x8 = __attribute__((ext_vector_type(8))) short;
using f32x4  = __attribute__((ext_vector_type(4))) float;

static __device__ __forceinline__ unsigned short f2bf(float f) {
  union { float f; unsigned int i; } v; v.f = f;
  unsigned int x = v.i;
  unsigned int r = x + 0x7FFFu + ((x >> 16) & 1u);
  return (unsigned short)(r >> 16);
}
static __device__ __forceinline__ float bf2f(unsigned short u) {
  union { unsigned int i; float f; } v;
  v.i = ((unsigned int)u) << 16;
  return v.f;
}

struct Params {
  const float* init_emb;
  const float* W1; const float* b1; const float* W2; const float* b2;
  const float* Rel; const float* M;
  const int* head; const int* tail;
  const int* src; const int* dst;
  float* out;
  int* cnt; int* rowptr; int* bsum; int* esrc; int* epos;
  float* dinv;
  unsigned short *hbuf1, *aggh, *aggl, *hbuf2, *xh, *xl, *Qbf;
  unsigned short *W1th, *W1tl, *W2th, *W2tl, *Mth;
};

union SharedU {
  unsigned short Ts[64 * TPAD];                                        // 17408 B (TQ)
  struct { unsigned short Qs[DIM * QPAD]; int Hidx[128]; int Tidx[128]; } pred;  // 35840 B
  int sd[256];                                                         // 1024 B (scan)
};

__global__ void __launch_bounds__(256, 4) k_mega(Params p) {
  __shared__ SharedU su;
  cg::grid_group grid = cg::this_grid();
  const int tid = threadIdx.x;
  const int nblk = gridDim.x;
  const int wave = tid >> 6, lane = tid & 63;
  const int l15 = lane & 15, quad = lane >> 4;
  union U { uint4 u; bf16x8 h; };

  // ================= P0: zero cnt + weight prep =================
  for (int g = blockIdx.x * 256 + tid; g < 65536; g += nblk * 256) {
    if (g < N_NODES) p.cnt[g] = 0;
    if (g < DIM * DIM) {
      int k = g >> 7, n = g & 127;
      int t = n * DIM + k;
      float w1 = p.W1[g]; unsigned short h1 = f2bf(w1);
      p.W1th[t] = h1; p.W1tl[t] = f2bf(w1 - bf2f(h1));
      float w2 = p.W2[g]; unsigned short h2 = f2bf(w2);
      p.W2th[t] = h2; p.W2tl[t] = f2bf(w2 - bf2f(h2));
      p.Mth[t] = f2bf(p.M[g]);
    }
  }
  grid.sync();

  // ================= P1: count+epos || gemm1 || decoder TQ =================
  for (int item = blockIdx.x; item < G_CNT + G_GEMM + G_TQ; item += nblk) {
    if (item < G_CNT) {
      int i0 = item * 1024 + tid * 4;
      if (i0 < N_EDGES) {
        int4 d4 = *(const int4*)(p.dst + i0);
        int4 e4;
        e4.x = atomicAdd(&p.cnt[d4.x], 1);
        e4.y = atomicAdd(&p.cnt[d4.y], 1);
        e4.z = atomicAdd(&p.cnt[d4.z], 1);
        e4.w = atomicAdd(&p.cnt[d4.w], 1);
        *(int4*)(p.epos + i0) = e4;
      }
    } else if (item < G_CNT + G_GEMM) {
      // gemm1: hbuf1 = init_emb @ W1 (hi/lo 3-term, bf16 out)
      int r0 = (item - G_CNT) * 128 + wave * 32;
      f32x4 acc[2][8];
      #pragma unroll
      for (int mt = 0; mt < 2; ++mt)
        #pragma unroll
        for (int nt = 0; nt < 8; ++nt) acc[mt][nt] = f32x4{0.f, 0.f, 0.f, 0.f};
      #pragma unroll
      for (int ks = 0; ks < 4; ++ks) {
        int k0 = ks * 32 + quad * 8;
        bf16x8 ah[2], al[2];
        #pragma unroll
        for (int mt = 0; mt < 2; ++mt) {
          int row = r0 + mt * 16 + l15;
          row = (row < N_NODES) ? row : (N_NODES - 1);
          const float* xp = p.init_emb + (size_t)row * DIM + k0;
          float xv[8];
          *(float4*)(xv)     = *(const float4*)(xp);
          *(float4*)(xv + 4) = *(const float4*)(xp + 4);
          #pragma unroll
          for (int j = 0; j < 8; ++j) {
            unsigned short h = f2bf(xv[j]);
            ah[mt][j] = (short)h;
            al[mt][j] = (short)f2bf(xv[j] - bf2f(h));
          }
        }
        #pragma unroll
        for (int nt = 0; nt < 8; ++nt) {
          U bh, bl;
          bh.u = *(const uint4*)(p.W1th + (nt * 16 + l15) * DIM + k0);
          bl.u = *(const uint4*)(p.W1tl + (nt * 16 + l15) * DIM + k0);
          #pragma unroll
          for (int mt = 0; mt < 2; ++mt) {
            acc[mt][nt] = __builtin_amdgcn_mfma_f32_16x16x32_bf16(ah[mt], bh.h, acc[mt][nt], 0, 0, 0);
            acc[mt][nt] = __builtin_amdgcn_mfma_f32_16x16x32_bf16(al[mt], bh.h, acc[mt][nt], 0, 0, 0);
            acc[mt][nt] = __builtin_amdgcn_mfma_f32_16x16x32_bf16(ah[mt], bl.h, acc[mt][nt], 0, 0, 0);
          }
        }
      }
      #pragma unroll
      for (int mt = 0; mt < 2; ++mt)
        #pragma unroll
        for (int reg = 0; reg < 4; ++reg) {
          int row = r0 + mt * 16 + quad * 4 + reg;
          if (row < N_NODES) {
            #pragma unroll
            for (int nt = 0; nt < 8; ++nt)
              p.hbuf1[(size_t)row * DIM + nt * 16 + l15] = f2bf(acc[mt][nt][reg]);
          }
        }
    } else {
      // decoder TQ: T_r = Rel_r @ M (LDS), Q_r = T_r @ Rel_r^T
      int rb = item - (G_CNT + G_GEMM);
      int r = rb >> 1, dblk = rb & 1;
      const float* Rr = p.Rel + (size_t)r * DIM * DIM;
      unsigned short* Qr = p.Qbf + (size_t)r * DIM * DIM;
      int dw = dblk * 64 + wave * 16;
      f32x4 acc[8];
      #pragma unroll
      for (int nt = 0; nt < 8; ++nt) acc[nt] = f32x4{0.f, 0.f, 0.f, 0.f};
      #pragma unroll
      for (int ks = 0; ks < 4; ++ks) {
        int k0 = ks * 32 + quad * 8;
        const float* ap = Rr + (size_t)(dw + l15) * DIM + k0;
        float av[8];
        *(float4*)(av)     = *(const float4*)(ap);
        *(float4*)(av + 4) = *(const float4*)(ap + 4);
        bf16x8 a;
        #pragma unroll
        for (int j = 0; j < 8; ++j) a[j] = (short)f2bf(av[j]);
        #pragma unroll
        for (int nt = 0; nt < 8; ++nt) {
          U b; b.u = *(const uint4*)(p.Mth + (nt * 16 + l15) * DIM + k0);
          acc[nt] = __builtin_amdgcn_mfma_f32_16x16x32_bf16(a, b.h, acc[nt], 0, 0, 0);
        }
      }
      #pragma unroll
      for (int nt = 0; nt < 8; ++nt)
        #pragma unroll
        for (int reg = 0; reg < 4; ++reg)
          su.Ts[(wave * 16 + quad * 4 + reg) * TPAD + nt * 16 + l15] = f2bf(acc[nt][reg]);
      __syncthreads();
      f32x4 qacc[8];
      #pragma unroll
      for (int nt = 0; nt < 8; ++nt) qacc[nt] = f32x4{0.f, 0.f, 0.f, 0.f};
      #pragma unroll
      for (int ks = 0; ks < 4; ++ks) {
        int k0 = ks * 32 + quad * 8;
        U a; a.u = *(const uint4*)(&su.Ts[(wave * 16 + l15) * TPAD + k0]);
        #pragma unroll
        for (int nt = 0; nt < 8; ++nt) {
          const float* bp = Rr + (size_t)(nt * 16 + l15) * DIM + k0;
          float bv[8];
          *(float4*)(bv)     = *(const float4*)(bp);
          *(float4*)(bv + 4) = *(const float4*)(bp + 4);
          bf16x8 b;
          #pragma unroll
          for (int j = 0; j < 8; ++j) b[j] = (short)f2bf(bv[j]);
          qacc[nt] = __builtin_amdgcn_mfma_f32_16x16x32_bf16(a.h, b, qacc[nt], 0, 0, 0);
        }
      }
      #pragma unroll
      for (int nt = 0; nt < 8; ++nt)
        #pragma unroll
        for (int reg = 0; reg < 4; ++reg)
          Qr[(size_t)(dw + quad * 4 + reg) * DIM + nt * 16 + l15] = f2bf(qacc[nt][reg]);
    }
  }
  grid.sync();

  // ================= P2a: scan reduce + dinv =================
  for (int item = blockIdx.x; item < NB_SCAN; item += nblk) {
    int base = item * 1024;
    int s = 0;
    #pragma unroll
    for (int i = 0; i < 4; ++i) {
      int idx = base + tid * 4 + i;
      if (idx < N_NODES) {
        int c = p.cnt[idx];
        s += c;
        p.dinv[idx] = rsqrtf((float)(c + 1));
      }
    }
    su.sd[tid] = s; __syncthreads();
    for (int off = 128; off > 0; off >>= 1) {
      if (tid < off) su.sd[tid] += su.sd[tid + off];
      __syncthreads();
    }
    if (tid == 0) p.bsum[item] = su.sd[0];
  }
  grid.sync();

  // ================= P2b: wave-parallel exclusive scan of bsum (block 0) =================
  if (blockIdx.x == 0 && tid < 64) {
    int v = (tid < NB_SCAN) ? p.bsum[tid] : 0;
    int inc = v;
    #pragma unroll
    for (int off = 1; off < 64; off <<= 1) {
      int y = __shfl_up(inc, off, 64);
      if (tid >= off) inc += y;
    }
    if (tid < NB_SCAN) p.bsum[tid] = inc - v;
    if (tid == NB_SCAN - 1) p.rowptr[N_NODES] = inc;
  }
  grid.sync();

  // ================= P2c: scan scatter -> rowptr =================
  for (int item = blockIdx.x; item < NB_SCAN; item += nblk) {
    int base = item * 1024;
    int v[4]; int s = 0;
    #pragma unroll
    for (int i = 0; i < 4; ++i) {
      int idx = base + tid * 4 + i;
      v[i] = (idx < N_NODES) ? p.cnt[idx] : 0;
      s += v[i];
    }
    su.sd[tid] = s; __syncthreads();
    for (int off = 1; off < 256; off <<= 1) {
      int y = (tid >= off) ? su.sd[tid - off] : 0;
      __syncthreads();
      su.sd[tid] += y;
      __syncthreads();
    }
    int pre = p.bsum[item] + su.sd[tid] - s;
    #pragma unroll
    for (int i = 0; i < 4; ++i) {
      int idx = base + tid * 4 + i;
      if (idx < N_NODES) p.rowptr[idx] = pre;
      pre += v[i];
    }
  }
  grid.sync();

  // ================= P3: CSR fill (no atomics) =================
  for (int item = blockIdx.x; item < G_CNT; item += nblk) {
    int i0 = item * 1024 + tid * 4;
    if (i0 < N_EDGES) {
      int4 s4 = *(const int4*)(p.src + i0);
      int4 d4 = *(const int4*)(p.dst + i0);
      int4 e4 = *(const int4*)(p.epos + i0);
      p.esrc[p.rowptr[d4.x] + e4.x] = s4.x;
      p.esrc[p.rowptr[d4.y] + e4.y] = s4.y;
      p.esrc[p.rowptr[d4.z] + e4.z] = s4.z;
      p.esrc[p.rowptr[d4.w] + e4.w] = s4.w;
    }
  }
  grid.sync();

  // ================= P4/P6: aggregate (macro-free lambda) =================
  auto agg_phase = [&](const unsigned short* hin, const float* bias,
                       unsigned short* outh, unsigned short* outl) {
    const ushort4* h4 = (const ushort4*)hin;
    int hw = tid >> 5, lane32 = tid & 31;
    for (int item = blockIdx.x; item < G_AGG; item += nblk) {
      int node = item * 8 + hw;
      if (node >= N_NODES) continue;
      float di = p.dinv[node];
      ushort4 hv = h4[(size_t)node * 32 + lane32];
      float ax = di * bf2f(hv.x), ay = di * bf2f(hv.y), az = di * bf2f(hv.z), aw = di * bf2f(hv.w);
      int e = p.rowptr[node], end = p.rowptr[node + 1];
      for (; e + 3 < end; e += 4) {
        int s0 = p.esrc[e], s1 = p.esrc[e + 1], s2 = p.esrc[e + 2], s3 = p.esrc[e + 3];
        float d0 = p.dinv[s0], d1 = p.dinv[s1], d2 = p.dinv[s2], d3 = p.dinv[s3];
        ushort4 v0 = h4[(size_t)s0 * 32 + lane32];
        ushort4 v1 = h4[(size_t)s1 * 32 + lane32];
        ushort4 v2 = h4[(size_t)s2 * 32 + lane32];
        ushort4 v3 = h4[(size_t)s3 * 32 + lane32];
        ax = fmaf(d0, bf2f(v0.x), ax); ay = fmaf(d0, bf2f(v0.y), ay); az = fmaf(d0, bf2f(v0.z), az); aw = fmaf(d0, bf2f(v0.w), aw);
        ax = fmaf(d1, bf2f(v1.x), ax); ay = fmaf(d1, bf2f(v1.y), ay); az = fmaf(d1, bf2f(v1.z), az); aw = fmaf(d1, bf2f(v1.w), aw);
        ax = fmaf(d2, bf2f(v2.x), ax); ay = fmaf(d2, bf2f(v2.y), ay); az = fmaf(d2, bf2f(v2.z), az); aw = fmaf(d2, bf2f(v2.w), aw);
        ax = fmaf(d3, bf2f(v3.x), ax); ay = fmaf(d3, bf2f(v3.y), ay); az = fmaf(d3, bf2f(v3.z), az); aw = fmaf(d3, bf2f(v3.w), aw);
      }
      for (; e < end; ++e) {
        int s = p.esrc[e];
        float ds = p.dinv[s];
        ushort4 vs = h4[(size_t)s * 32 + lane32];
        ax = fmaf(ds, bf2f(vs.x), ax); ay = fmaf(ds, bf2f(vs.y), ay);
        az = fmaf(ds, bf2f(vs.z), az); aw = fmaf(ds, bf2f(vs.w), aw);
      }
      float4 bb = ((const float4*)bias)[lane32];
      float vx = fmaf(di, ax, bb.x), vy = fmaf(di, ay, bb.y);
      float vz = fmaf(di, az, bb.z), vw = fmaf(di, aw, bb.w);
      ushort4 hi4, lo4;
      hi4.x = f2bf(vx); lo4.x = f2bf(vx - bf2f(hi4.x));
      hi4.y = f2bf(vy); lo4.y = f2bf(vy - bf2f(hi4.y));
      hi4.z = f2bf(vz); lo4.z = f2bf(vz - bf2f(hi4.z));
      hi4.w = f2bf(vw); lo4.w = f2bf(vw - bf2f(hi4.w));
      ((ushort4*)outh)[(size_t)node * 32 + lane32] = hi4;
      ((ushort4*)outl)[(size_t)node * 32 + lane32] = lo4;
    }
  };

  // P4: agg1
  agg_phase(p.hbuf1, p.b1, p.aggh, p.aggl);
  grid.sync();

  // ================= P5: gemm2 from hi/lo planes =================
  for (int item = blockIdx.x; item < G_GEMM; item += nblk) {
    int r0 = item * 128 + wave * 32;
    f32x4 acc[2][8];
    #pragma unroll
    for (int mt = 0; mt < 2; ++mt)
      #pragma unroll
      for (int nt = 0; nt < 8; ++nt) acc[mt][nt] = f32x4{0.f, 0.f, 0.f, 0.f};
    #pragma unroll
    for (int ks = 0; ks < 4; ++ks) {
      int k0 = ks * 32 + quad * 8;
      U ah[2], al[2];
      #pragma unroll
      for (int mt = 0; mt < 2; ++mt) {
        int row = r0 + mt * 16 + l15;
        row = (row < N_NODES) ? row : (N_NODES - 1);
        ah[mt].u = *(const uint4*)(p.aggh + (size_t)row * DIM + k0);
        al[mt].u = *(const uint4*)(p.aggl + (size_t)row * DIM + k0);
      }
      #pragma unroll
      for (int nt = 0; nt < 8; ++nt) {
        U bh, bl;
        bh.u = *(const uint4*)(p.W2th + (nt * 16 + l15) * DIM + k0);
        bl.u = *(const uint4*)(p.W2tl + (nt * 16 + l15) * DIM + k0);
        #pragma unroll
        for (int mt = 0; mt < 2; ++mt) {
          acc[mt][nt] = __builtin_amdgcn_mfma_f32_16x16x32_bf16(ah[mt].h, bh.h, acc[mt][nt], 0, 0, 0);
          acc[mt][nt] = __builtin_amdgcn_mfma_f32_16x16x32_bf16(al[mt].h, bh.h, acc[mt][nt], 0, 0, 0);
          acc[mt][nt] = __builtin_amdgcn_mfma_f32_16x16x32_bf16(ah[mt].h, bl.h, acc[mt][nt], 0, 0, 0);
        }
      }
    }
    #pragma unroll
    for (int mt = 0; mt < 2; ++mt)
      #pragma unroll
      for (int reg = 0; reg < 4; ++reg) {
        int row = r0 + mt * 16 + quad * 4 + reg;
        if (row < N_NODES) {
          #pragma unroll
          for (int nt = 0; nt < 8; ++nt)
            p.hbuf2[(size_t)row * DIM + nt * 16 + l15] = f2bf(acc[mt][nt][reg]);
        }
      }
  }
  grid.sync();

  // P6: agg2
  agg_phase(p.hbuf2, p.b2, p.xh, p.xl);
  grid.sync();

  // ================= P7: predict (inline gather from hi/lo planes) =================
  for (int item = blockIdx.x; item < G_PRED; item += nblk) {
    int bb = item & 15, r = item >> 4;
    const unsigned short* Qr = p.Qbf + (size_t)r * DIM * DIM;
    __syncthreads();  // protect Qs/idx reuse across loop iterations
    for (int i = tid; i < DIM * DIM / 8; i += 256) {
      int d = i >> 4, c = (i & 15) * 8;
      uint4 v = ((const uint4*)Qr)[i];
      *(uint4*)(&su.pred.Qs[d * QPAD + c]) = v;
    }
    if (tid < 128) su.pred.Hidx[tid] = p.head[bb * 128 + tid];
    else su.pred.Tidx[tid - 128] = p.tail[bb * 128 + tid - 128];
    __syncthreads();
    int t0r = su.pred.Tidx[wave * 32 + l15];
    int t1r = su.pred.Tidx[wave * 32 + 16 + l15];

    f32x4 acc[2][8];
    #pragma unroll
    for (int m = 0; m < 2; ++m)
      #pragma unroll
      for (int n = 0; n < 8; ++n) acc[m][n] = f32x4{0.f, 0.f, 0.f, 0.f};

    #pragma unroll
    for (int ks = 0; ks < 4; ++ks) {
      int eoff = ks * 32 + quad * 8;
      U a0, a1;
      a0.u = *(const uint4*)(p.xh + (size_t)t0r * DIM + eoff);   // tail = hi plane
      a1.u = *(const uint4*)(p.xh + (size_t)t1r * DIM + eoff);
      #pragma unroll
      for (int nt = 0; nt < 8; ++nt) {
        U b; b.u = *(const uint4*)(&su.pred.Qs[(nt * 16 + l15) * QPAD + eoff]);
        acc[0][nt] = __builtin_amdgcn_mfma_f32_16x16x32_bf16(a0.h, b.h, acc[0][nt], 0, 0, 0);
        acc[1][nt] = __builtin_amdgcn_mfma_f32_16x16x32_bf16(a1.h, b.h, acc[1][nt], 0, 0, 0);
      }
    }

    int bbase = bb * 128 + wave * 32;
    #pragma unroll
    for (int m = 0; m < 2; ++m) {
      #pragma unroll
      for (int reg = 0; reg < 4; ++reg) {
        int bl = wave * 32 + m * 16 + quad * 4 + reg;
        int hrow = su.pred.Hidx[bl];
        float s = 0.f;
        #pragma unroll
        for (int nt = 0; nt < 8; ++nt) {
          size_t idx = (size_t)hrow * DIM + nt * 16 + l15;
          s += (bf2f(p.xh[idx]) + bf2f(p.xl[idx])) * acc[m][nt][reg];  // head = hi+lo
        }
        #pragma unroll
        for (int off = 1; off < 16; off <<= 1) s += __shfl_xor(s, off, 64);
        if (l15 == 0) p.out[(size_t)(bbase + m * 16 + quad * 4 + reg) * N_REL + r] = s;
      }
    }
  }
}

// ---------------- launch ----------------

extern "C" void kernel_launch(void* const* d_in, const int* in_sizes, int n_in,
                              void* d_out, int out_size, void* d_ws, size_t ws_size,
                              hipStream_t stream) {
  (void)in_sizes; (void)n_in; (void)out_size; (void)ws_size;
  Params prm;
  prm.init_emb = (const float*)d_in[0];
  prm.W1  = (const float*)d_in[1];
  prm.b1  = (const float*)d_in[2];
  prm.W2  = (const float*)d_in[3];
  prm.b2  = (const float*)d_in[4];
  prm.Rel = (const float*)d_in[5];
  prm.M   = (const float*)d_in[6];
  prm.head = (const int*)d_in[7];
  prm.tail = (const int*)d_in[8];
  prm.src  = (const int*)d_in[9];
  prm.dst  = prm.src + N_EDGES;
  prm.out  = (float*)d_out;

  char* p = (char*)d_ws;
  auto alloc = [&](size_t bytes) { char* q = p; p += (bytes + 511) & ~(size_t)511; return q; };
  prm.cnt    = (int*)alloc((size_t)N_NODES * 4);
  prm.rowptr = (int*)alloc((size_t)(N_NODES + 1) * 4);
  prm.bsum   = (int*)alloc(64 * 4);
  prm.esrc   = (int*)alloc((size_t)N_EDGES * 4);
  prm.epos   = (int*)alloc((size_t)N_EDGES * 4);
  prm.dinv   = (float*)alloc((size_t)N_NODES * 4);
  prm.hbuf1  = (unsigned short*)alloc((size_t)N_NODES * DIM * 2);
  prm.aggh   = (unsigned short*)alloc((size_t)N_NODES * DIM * 2);
  prm.aggl   = (unsigned short*)alloc((size_t)N_NODES * DIM * 2);
  prm.hbuf2  = (unsigned short*)alloc((size_t)N_NODES * DIM * 2);
  prm.xh     = (unsigned short*)alloc((size_t)N_NODES * DIM * 2);
  prm.xl     = (unsigned short*)alloc((size_t)N_NODES * DIM * 2);
  prm.Qbf    = (unsigned short*)alloc((size_t)N_REL * DIM * DIM * 2);
  prm.W1th   = (unsigned short*)alloc((size_t)DIM * DIM * 2);
  prm.W1tl   = (unsigned short*)alloc((size_t)DIM * DIM * 2);
  prm.W2th   = (unsigned short*)alloc((size_t)DIM * DIM * 2);
  prm.W2tl   = (unsigned short*)alloc((size_t)DIM * DIM * 2);
  prm.Mth    = (unsigned short*)alloc((size_t)DIM * DIM * 2);

  int blocksPerCU = 0;
  if (hipOccupancyMaxActiveBlocksPerMultiprocessor(&blocksPerCU, (const void*)k_mega, 256, 0)
      != hipSuccess || blocksPerCU < 1)
    blocksPerCU = 4;  // LDS 35840 B -> 4 blocks/CU; __launch_bounds__(256,4) caps VGPR at 128
  int grid = blocksPerCU * 256;
  if (grid > 1024) grid = 1024;

  void* args[] = { &prm };
  hipLaunchCooperativeKernel((const void*)k_mega, dim3(grid), dim3(256), args, 0, stream);
}

// Round 11
// 439.542 us; speedup vs baseline: 2.2887x; 2.2887x over previous
//
#include <hip/hip_runtime.h>
#include <hip/hip_cooperative_groups.h>

namespace cg = cooperative_groups;

#define N_NODES 50000
#define N_EDGES 800000
#define DIM 128
#define N_REL 86
#define BATCH 2048

#define TPAD 136              // 128+8 bf16: 272 B row stride -> 2-way bank alias (free)
#define QPAD 136

#define G_CNT  782            // ceil(800000/1024), 4 edges/thread
#define G_GEMM 391            // ceil(50000/128)
#define G_TQ   172            // 86 relations x 2 d-blocks
#define NB_SCAN 49            // ceil(50000/1024)

using bf16x8 = __attribute__((ext_vector_type(8))) short;
using f32x4  = __attribute__((ext_vector_type(4))) float;

static __device__ __forceinline__ unsigned short f2bf(float f) {
  union { float f; unsigned int i; } v; v.f = f;
  unsigned int x = v.i;
  unsigned int r = x + 0x7FFFu + ((x >> 16) & 1u);
  return (unsigned short)(r >> 16);
}
static __device__ __forceinline__ float bf2f(unsigned short u) {
  union { unsigned int i; float f; } v;
  v.i = ((unsigned int)u) << 16;
  return v.f;
}

struct ParamsA {
  const float* init_emb;
  const float* W1; const float* W2; const float* M;
  const float* Rel;
  const int* src; const int* dst;
  int* cnt; int* rowptr; int* bsum; int* esrc; int* epos;
  float* dinv;
  unsigned short *hbuf1, *Qbf;
  unsigned short *W1th, *W1tl, *W2th, *W2tl, *Mth;
};

// ============ cooperative prefix: prep -> count||TQ -> scans -> fill||gemm1 ============

__global__ void __launch_bounds__(256) k_coopA(ParamsA p) {
  __shared__ __align__(16) union { unsigned short Ts[64 * TPAD]; int sd[256]; } su;
  cg::grid_group grid = cg::this_grid();
  const int tid = threadIdx.x;
  const int nblk = gridDim.x;
  const int wave = tid >> 6, lane = tid & 63;
  const int l15 = lane & 15, quad = lane >> 4;
  union U { uint4 u; bf16x8 h; };

  // ---- P0: zero cnt + weight prep ----
  for (int g = blockIdx.x * 256 + tid; g < 65536; g += nblk * 256) {
    if (g < N_NODES) p.cnt[g] = 0;
    if (g < DIM * DIM) {
      int k = g >> 7, n = g & 127;
      int t = n * DIM + k;
      float w1 = p.W1[g]; unsigned short h1 = f2bf(w1);
      p.W1th[t] = h1; p.W1tl[t] = f2bf(w1 - bf2f(h1));
      float w2 = p.W2[g]; unsigned short h2 = f2bf(w2);
      p.W2th[t] = h2; p.W2tl[t] = f2bf(w2 - bf2f(h2));
      p.Mth[t] = f2bf(p.M[g]);
    }
  }
  grid.sync();

  // ---- P1: count+epos || decoder TQ ----
  for (int item = blockIdx.x; item < G_CNT + G_TQ; item += nblk) {
    if (item < G_CNT) {
      int i0 = item * 1024 + tid * 4;
      if (i0 < N_EDGES) {
        int4 d4 = *(const int4*)(p.dst + i0);
        int4 e4;
        e4.x = atomicAdd(&p.cnt[d4.x], 1);
        e4.y = atomicAdd(&p.cnt[d4.y], 1);
        e4.z = atomicAdd(&p.cnt[d4.z], 1);
        e4.w = atomicAdd(&p.cnt[d4.w], 1);
        *(int4*)(p.epos + i0) = e4;
      }
    } else {
      __syncthreads();  // protect Ts reuse across loop iterations
      int rb = item - G_CNT;
      int r = rb >> 1, dblk = rb & 1;
      const float* Rr = p.Rel + (size_t)r * DIM * DIM;
      unsigned short* Qr = p.Qbf + (size_t)r * DIM * DIM;
      int dw = dblk * 64 + wave * 16;
      f32x4 acc[8];
      #pragma unroll
      for (int nt = 0; nt < 8; ++nt) acc[nt] = f32x4{0.f, 0.f, 0.f, 0.f};
      #pragma unroll
      for (int ks = 0; ks < 4; ++ks) {
        int k0 = ks * 32 + quad * 8;
        const float* ap = Rr + (size_t)(dw + l15) * DIM + k0;
        float av[8];
        *(float4*)(av)     = *(const float4*)(ap);
        *(float4*)(av + 4) = *(const float4*)(ap + 4);
        bf16x8 a;
        #pragma unroll
        for (int j = 0; j < 8; ++j) a[j] = (short)f2bf(av[j]);
        #pragma unroll
        for (int nt = 0; nt < 8; ++nt) {
          U b; b.u = *(const uint4*)(p.Mth + (nt * 16 + l15) * DIM + k0);
          acc[nt] = __builtin_amdgcn_mfma_f32_16x16x32_bf16(a, b.h, acc[nt], 0, 0, 0);
        }
      }
      #pragma unroll
      for (int nt = 0; nt < 8; ++nt)
        #pragma unroll
        for (int reg = 0; reg < 4; ++reg)
          su.Ts[(wave * 16 + quad * 4 + reg) * TPAD + nt * 16 + l15] = f2bf(acc[nt][reg]);
      __syncthreads();
      f32x4 qacc[8];
      #pragma unroll
      for (int nt = 0; nt < 8; ++nt) qacc[nt] = f32x4{0.f, 0.f, 0.f, 0.f};
      #pragma unroll
      for (int ks = 0; ks < 4; ++ks) {
        int k0 = ks * 32 + quad * 8;
        U a; a.u = *(const uint4*)(&su.Ts[(wave * 16 + l15) * TPAD + k0]);
        #pragma unroll
        for (int nt = 0; nt < 8; ++nt) {
          const float* bp = Rr + (size_t)(nt * 16 + l15) * DIM + k0;
          float bv[8];
          *(float4*)(bv)     = *(const float4*)(bp);
          *(float4*)(bv + 4) = *(const float4*)(bp + 4);
          bf16x8 b;
          #pragma unroll
          for (int j = 0; j < 8; ++j) b[j] = (short)f2bf(bv[j]);
          qacc[nt] = __builtin_amdgcn_mfma_f32_16x16x32_bf16(a.h, b, qacc[nt], 0, 0, 0);
        }
      }
      #pragma unroll
      for (int nt = 0; nt < 8; ++nt)
        #pragma unroll
        for (int reg = 0; reg < 4; ++reg)
          Qr[(size_t)(dw + quad * 4 + reg) * DIM + nt * 16 + l15] = f2bf(qacc[nt][reg]);
    }
  }
  grid.sync();

  // ---- P2a: scan reduce + dinv ----
  for (int item = blockIdx.x; item < NB_SCAN; item += nblk) {
    int base = item * 1024;
    int s = 0;
    #pragma unroll
    for (int i = 0; i < 4; ++i) {
      int idx = base + tid * 4 + i;
      if (idx < N_NODES) {
        int c = p.cnt[idx];
        s += c;
        p.dinv[idx] = rsqrtf((float)(c + 1));
      }
    }
    su.sd[tid] = s; __syncthreads();
    for (int off = 128; off > 0; off >>= 1) {
      if (tid < off) su.sd[tid] += su.sd[tid + off];
      __syncthreads();
    }
    if (tid == 0) p.bsum[item] = su.sd[0];
  }
  grid.sync();

  // ---- P2b: wave-parallel exclusive scan of bsum (block 0) ----
  if (blockIdx.x == 0 && tid < 64) {
    int v = (tid < NB_SCAN) ? p.bsum[tid] : 0;
    int inc = v;
    #pragma unroll
    for (int off = 1; off < 64; off <<= 1) {
      int y = __shfl_up(inc, off, 64);
      if (tid >= off) inc += y;
    }
    if (tid < NB_SCAN) p.bsum[tid] = inc - v;
    if (tid == NB_SCAN - 1) p.rowptr[N_NODES] = inc;
  }
  grid.sync();

  // ---- P2c: scan scatter -> rowptr ----
  for (int item = blockIdx.x; item < NB_SCAN; item += nblk) {
    int base = item * 1024;
    int v[4]; int s = 0;
    #pragma unroll
    for (int i = 0; i < 4; ++i) {
      int idx = base + tid * 4 + i;
      v[i] = (idx < N_NODES) ? p.cnt[idx] : 0;
      s += v[i];
    }
    su.sd[tid] = s; __syncthreads();
    for (int off = 1; off < 256; off <<= 1) {
      int y = (tid >= off) ? su.sd[tid - off] : 0;
      __syncthreads();
      su.sd[tid] += y;
      __syncthreads();
    }
    int pre = p.bsum[item] + su.sd[tid] - s;
    #pragma unroll
    for (int i = 0; i < 4; ++i) {
      int idx = base + tid * 4 + i;
      if (idx < N_NODES) p.rowptr[idx] = pre;
      pre += v[i];
    }
  }
  grid.sync();

  // ---- P3: fill (no atomics) || gemm1 ----
  for (int item = blockIdx.x; item < G_CNT + G_GEMM; item += nblk) {
    if (item < G_CNT) {
      int i0 = item * 1024 + tid * 4;
      if (i0 < N_EDGES) {
        int4 s4 = *(const int4*)(p.src + i0);
        int4 d4 = *(const int4*)(p.dst + i0);
        int4 e4 = *(const int4*)(p.epos + i0);
        p.esrc[p.rowptr[d4.x] + e4.x] = s4.x;
        p.esrc[p.rowptr[d4.y] + e4.y] = s4.y;
        p.esrc[p.rowptr[d4.z] + e4.z] = s4.z;
        p.esrc[p.rowptr[d4.w] + e4.w] = s4.w;
      }
    } else {
      int r0 = (item - G_CNT) * 128 + wave * 32;
      f32x4 acc[2][8];
      #pragma unroll
      for (int mt = 0; mt < 2; ++mt)
        #pragma unroll
        for (int nt = 0; nt < 8; ++nt) acc[mt][nt] = f32x4{0.f, 0.f, 0.f, 0.f};
      #pragma unroll
      for (int ks = 0; ks < 4; ++ks) {
        int k0 = ks * 32 + quad * 8;
        bf16x8 ah[2], al[2];
        #pragma unroll
        for (int mt = 0; mt < 2; ++mt) {
          int row = r0 + mt * 16 + l15;
          row = (row < N_NODES) ? row : (N_NODES - 1);
          const float* xp = p.init_emb + (size_t)row * DIM + k0;
          float xv[8];
          *(float4*)(xv)     = *(const float4*)(xp);
          *(float4*)(xv + 4) = *(const float4*)(xp + 4);
          #pragma unroll
          for (int j = 0; j < 8; ++j) {
            unsigned short h = f2bf(xv[j]);
            ah[mt][j] = (short)h;
            al[mt][j] = (short)f2bf(xv[j] - bf2f(h));
          }
        }
        #pragma unroll
        for (int nt = 0; nt < 8; ++nt) {
          U bh, bl;
          bh.u = *(const uint4*)(p.W1th + (nt * 16 + l15) * DIM + k0);
          bl.u = *(const uint4*)(p.W1tl + (nt * 16 + l15) * DIM + k0);
          #pragma unroll
          for (int mt = 0; mt < 2; ++mt) {
            acc[mt][nt] = __builtin_amdgcn_mfma_f32_16x16x32_bf16(ah[mt], bh.h, acc[mt][nt], 0, 0, 0);
            acc[mt][nt] = __builtin_amdgcn_mfma_f32_16x16x32_bf16(al[mt], bh.h, acc[mt][nt], 0, 0, 0);
            acc[mt][nt] = __builtin_amdgcn_mfma_f32_16x16x32_bf16(ah[mt], bl.h, acc[mt][nt], 0, 0, 0);
          }
        }
      }
      #pragma unroll
      for (int mt = 0; mt < 2; ++mt)
        #pragma unroll
        for (int reg = 0; reg < 4; ++reg) {
          int row = r0 + mt * 16 + quad * 4 + reg;
          if (row < N_NODES) {
            #pragma unroll
            for (int nt = 0; nt < 8; ++nt)
              p.hbuf1[(size_t)row * DIM + nt * 16 + l15] = f2bf(acc[mt][nt][reg]);
          }
        }
    }
  }
}

// ============ standalone phases (round-9 proven code, unchanged) ============

__global__ __launch_bounds__(256) void k_agg_hl(const unsigned short* __restrict__ h,
                                                const int* __restrict__ rowptr,
                                                const int* __restrict__ esrc, const float* __restrict__ dinv,
                                                const float* __restrict__ bias,
                                                unsigned short* __restrict__ outh,
                                                unsigned short* __restrict__ outl) {
  int node = blockIdx.x * 8 + (threadIdx.x >> 5);
  if (node >= N_NODES) return;
  int lane = threadIdx.x & 31;
  const ushort4* h4 = (const ushort4*)h;
  float di = dinv[node];
  ushort4 hv = h4[(size_t)node * 32 + lane];
  float ax = di * bf2f(hv.x), ay = di * bf2f(hv.y), az = di * bf2f(hv.z), aw = di * bf2f(hv.w);
  int e = rowptr[node], end = rowptr[node + 1];
  for (; e + 3 < end; e += 4) {
    int s0 = esrc[e], s1 = esrc[e + 1], s2 = esrc[e + 2], s3 = esrc[e + 3];
    float d0 = dinv[s0], d1 = dinv[s1], d2 = dinv[s2], d3 = dinv[s3];
    ushort4 v0 = h4[(size_t)s0 * 32 + lane];
    ushort4 v1 = h4[(size_t)s1 * 32 + lane];
    ushort4 v2 = h4[(size_t)s2 * 32 + lane];
    ushort4 v3 = h4[(size_t)s3 * 32 + lane];
    ax = fmaf(d0, bf2f(v0.x), ax); ay = fmaf(d0, bf2f(v0.y), ay); az = fmaf(d0, bf2f(v0.z), az); aw = fmaf(d0, bf2f(v0.w), aw);
    ax = fmaf(d1, bf2f(v1.x), ax); ay = fmaf(d1, bf2f(v1.y), ay); az = fmaf(d1, bf2f(v1.z), az); aw = fmaf(d1, bf2f(v1.w), aw);
    ax = fmaf(d2, bf2f(v2.x), ax); ay = fmaf(d2, bf2f(v2.y), ay); az = fmaf(d2, bf2f(v2.z), az); aw = fmaf(d2, bf2f(v2.w), aw);
    ax = fmaf(d3, bf2f(v3.x), ax); ay = fmaf(d3, bf2f(v3.y), ay); az = fmaf(d3, bf2f(v3.z), az); aw = fmaf(d3, bf2f(v3.w), aw);
  }
  for (; e < end; ++e) {
    int s = esrc[e];
    float ds = dinv[s];
    ushort4 vs = h4[(size_t)s * 32 + lane];
    ax = fmaf(ds, bf2f(vs.x), ax); ay = fmaf(ds, bf2f(vs.y), ay);
    az = fmaf(ds, bf2f(vs.z), az); aw = fmaf(ds, bf2f(vs.w), aw);
  }
  float4 bb = ((const float4*)bias)[lane];
  float vx = fmaf(di, ax, bb.x), vy = fmaf(di, ay, bb.y);
  float vz = fmaf(di, az, bb.z), vw = fmaf(di, aw, bb.w);
  ushort4 hi4, lo4;
  hi4.x = f2bf(vx); lo4.x = f2bf(vx - bf2f(hi4.x));
  hi4.y = f2bf(vy); lo4.y = f2bf(vy - bf2f(hi4.y));
  hi4.z = f2bf(vz); lo4.z = f2bf(vz - bf2f(hi4.z));
  hi4.w = f2bf(vw); lo4.w = f2bf(vw - bf2f(hi4.w));
  ((ushort4*)outh)[(size_t)node * 32 + lane] = hi4;
  ((ushort4*)outl)[(size_t)node * 32 + lane] = lo4;
}

__global__ __launch_bounds__(256) void k_gemm_hl(const unsigned short* __restrict__ xh,
                                                 const unsigned short* __restrict__ xl,
                                                 const unsigned short* __restrict__ Wth,
                                                 const unsigned short* __restrict__ Wtl,
                                                 unsigned short* __restrict__ out, int nrows) {
  int wave = threadIdx.x >> 6, lane = threadIdx.x & 63;
  int l15 = lane & 15, quad = lane >> 4;
  int r0 = blockIdx.x * 128 + wave * 32;
  f32x4 acc[2][8];
  #pragma unroll
  for (int mt = 0; mt < 2; ++mt)
    #pragma unroll
    for (int nt = 0; nt < 8; ++nt) acc[mt][nt] = f32x4{0.f, 0.f, 0.f, 0.f};
  union U { uint4 u; bf16x8 h; };
  #pragma unroll
  for (int ks = 0; ks < 4; ++ks) {
    int k0 = ks * 32 + quad * 8;
    U ah[2], al[2];
    #pragma unroll
    for (int mt = 0; mt < 2; ++mt) {
      int row = r0 + mt * 16 + l15;
      row = (row < nrows) ? row : (nrows - 1);
      ah[mt].u = *(const uint4*)(xh + (size_t)row * DIM + k0);
      al[mt].u = *(const uint4*)(xl + (size_t)row * DIM + k0);
    }
    #pragma unroll
    for (int nt = 0; nt < 8; ++nt) {
      U bh, bl;
      bh.u = *(const uint4*)(Wth + (nt * 16 + l15) * DIM + k0);
      bl.u = *(const uint4*)(Wtl + (nt * 16 + l15) * DIM + k0);
      #pragma unroll
      for (int mt = 0; mt < 2; ++mt) {
        acc[mt][nt] = __builtin_amdgcn_mfma_f32_16x16x32_bf16(ah[mt].h, bh.h, acc[mt][nt], 0, 0, 0);
        acc[mt][nt] = __builtin_amdgcn_mfma_f32_16x16x32_bf16(al[mt].h, bh.h, acc[mt][nt], 0, 0, 0);
        acc[mt][nt] = __builtin_amdgcn_mfma_f32_16x16x32_bf16(ah[mt].h, bl.h, acc[mt][nt], 0, 0, 0);
      }
    }
  }
  #pragma unroll
  for (int mt = 0; mt < 2; ++mt)
    #pragma unroll
    for (int reg = 0; reg < 4; ++reg) {
      int row = r0 + mt * 16 + quad * 4 + reg;
      if (row < nrows) {
        #pragma unroll
        for (int nt = 0; nt < 8; ++nt)
          out[(size_t)row * DIM + nt * 16 + l15] = f2bf(acc[mt][nt][reg]);
      }
    }
}

__global__ __launch_bounds__(256) void k_predict_mfma(const unsigned short* __restrict__ xh,
                                                      const unsigned short* __restrict__ xl,
                                                      const int* __restrict__ head,
                                                      const int* __restrict__ tail,
                                                      const unsigned short* __restrict__ Qbf,
                                                      float* __restrict__ out) {
  __shared__ __align__(16) unsigned short Qs[DIM * QPAD];
  __shared__ int Hidx[128];
  __shared__ int Tidx[128];
  int r = blockIdx.y;
  const unsigned short* Qr = Qbf + (size_t)r * DIM * DIM;
  for (int i = threadIdx.x; i < DIM * DIM / 8; i += 256) {
    int d = i >> 4, c = (i & 15) * 8;
    uint4 v = ((const uint4*)Qr)[i];
    *(uint4*)(&Qs[d * QPAD + c]) = v;
  }
  if (threadIdx.x < 128) Hidx[threadIdx.x] = head[blockIdx.x * 128 + threadIdx.x];
  else Tidx[threadIdx.x - 128] = tail[blockIdx.x * 128 + threadIdx.x - 128];
  __syncthreads();
  int wave = threadIdx.x >> 6, lane = threadIdx.x & 63;
  int l15 = lane & 15, quad = lane >> 4;
  int t0r = Tidx[wave * 32 + l15];
  int t1r = Tidx[wave * 32 + 16 + l15];

  f32x4 acc[2][8];
  #pragma unroll
  for (int m = 0; m < 2; ++m)
    #pragma unroll
    for (int n = 0; n < 8; ++n) acc[m][n] = f32x4{0.f, 0.f, 0.f, 0.f};

  union U { uint4 u; bf16x8 h; };
  #pragma unroll
  for (int ks = 0; ks < 4; ++ks) {
    int eoff = ks * 32 + quad * 8;
    U a0, a1;
    a0.u = *(const uint4*)(xh + (size_t)t0r * DIM + eoff);   // tail = hi plane
    a1.u = *(const uint4*)(xh + (size_t)t1r * DIM + eoff);
    #pragma unroll
    for (int nt = 0; nt < 8; ++nt) {
      U b; b.u = *(const uint4*)(&Qs[(nt * 16 + l15) * QPAD + eoff]);
      acc[0][nt] = __builtin_amdgcn_mfma_f32_16x16x32_bf16(a0.h, b.h, acc[0][nt], 0, 0, 0);
      acc[1][nt] = __builtin_amdgcn_mfma_f32_16x16x32_bf16(a1.h, b.h, acc[1][nt], 0, 0, 0);
    }
  }

  int bbase = blockIdx.x * 128 + wave * 32;
  #pragma unroll
  for (int m = 0; m < 2; ++m) {
    #pragma unroll
    for (int reg = 0; reg < 4; ++reg) {
      int bl = wave * 32 + m * 16 + quad * 4 + reg;
      int hrow = Hidx[bl];
      float s = 0.f;
      #pragma unroll
      for (int nt = 0; nt < 8; ++nt) {
        size_t idx = (size_t)hrow * DIM + nt * 16 + l15;
        s += (bf2f(xh[idx]) + bf2f(xl[idx])) * acc[m][nt][reg];  // head = hi+lo
      }
      #pragma unroll
      for (int off = 1; off < 16; off <<= 1) s += __shfl_xor(s, off, 64);
      if (l15 == 0) out[(size_t)(bbase + m * 16 + quad * 4 + reg) * N_REL + r] = s;
    }
  }
}

// ---------------- launch ----------------

extern "C" void kernel_launch(void* const* d_in, const int* in_sizes, int n_in,
                              void* d_out, int out_size, void* d_ws, size_t ws_size,
                              hipStream_t stream) {
  (void)in_sizes; (void)n_in; (void)out_size; (void)ws_size;
  const float* b1 = (const float*)d_in[2];
  const float* b2 = (const float*)d_in[4];
  const int* head = (const int*)d_in[7];
  const int* tail = (const int*)d_in[8];
  float* out = (float*)d_out;

  ParamsA pa;
  pa.init_emb = (const float*)d_in[0];
  pa.W1 = (const float*)d_in[1];
  pa.W2 = (const float*)d_in[3];
  pa.Rel = (const float*)d_in[5];
  pa.M = (const float*)d_in[6];
  pa.src = (const int*)d_in[9];
  pa.dst = pa.src + N_EDGES;

  char* p = (char*)d_ws;
  auto alloc = [&](size_t bytes) { char* q = p; p += (bytes + 511) & ~(size_t)511; return q; };
  pa.cnt    = (int*)alloc((size_t)N_NODES * 4);
  pa.rowptr = (int*)alloc((size_t)(N_NODES + 1) * 4);
  pa.bsum   = (int*)alloc(64 * 4);
  pa.esrc   = (int*)alloc((size_t)N_EDGES * 4);
  pa.epos   = (int*)alloc((size_t)N_EDGES * 4);
  pa.dinv   = (float*)alloc((size_t)N_NODES * 4);
  pa.hbuf1  = (unsigned short*)alloc((size_t)N_NODES * DIM * 2);
  unsigned short* aggh  = (unsigned short*)alloc((size_t)N_NODES * DIM * 2);
  unsigned short* aggl  = (unsigned short*)alloc((size_t)N_NODES * DIM * 2);
  unsigned short* hbuf2 = (unsigned short*)alloc((size_t)N_NODES * DIM * 2);
  unsigned short* xh    = (unsigned short*)alloc((size_t)N_NODES * DIM * 2);
  unsigned short* xl    = (unsigned short*)alloc((size_t)N_NODES * DIM * 2);
  pa.Qbf    = (unsigned short*)alloc((size_t)N_REL * DIM * DIM * 2);
  pa.W1th   = (unsigned short*)alloc((size_t)DIM * DIM * 2);
  pa.W1tl   = (unsigned short*)alloc((size_t)DIM * DIM * 2);
  pa.W2th   = (unsigned short*)alloc((size_t)DIM * DIM * 2);
  pa.W2tl   = (unsigned short*)alloc((size_t)DIM * DIM * 2);
  pa.Mth    = (unsigned short*)alloc((size_t)DIM * DIM * 2);

  int blocksPerCU = 0;
  if (hipOccupancyMaxActiveBlocksPerMultiprocessor(&blocksPerCU, (const void*)k_coopA, 256, 0)
      != hipSuccess || blocksPerCU < 1)
    blocksPerCU = 4;
  int grid = blocksPerCU * 256;
  if (grid > 1184) grid = 1184;  // P3 has 1173 work items; larger grids only idle at syncs

  void* args[] = { &pa };
  hipLaunchCooperativeKernel((const void*)k_coopA, dim3(grid), dim3(256), args, 0, stream);

  // agg1 -> gemm2 -> agg2 -> predict (regular launches, own register/occupancy profiles)
  k_agg_hl<<<(N_NODES + 7) / 8, 256, 0, stream>>>(pa.hbuf1, pa.rowptr, pa.esrc, pa.dinv, b1, aggh, aggl);
  k_gemm_hl<<<(N_NODES + 127) / 128, 256, 0, stream>>>(aggh, aggl, pa.W2th, pa.W2tl, hbuf2, N_NODES);
  k_agg_hl<<<(N_NODES + 7) / 8, 256, 0, stream>>>(hbuf2, pa.rowptr, pa.esrc, pa.dinv, b2, xh, xl);
  k_predict_mfma<<<dim3(BATCH / 128, N_REL), 256, 0, stream>>>(xh, xl, head, tail, pa.Qbf, out);
}

// Round 12
// 312.039 us; speedup vs baseline: 3.2240x; 1.4086x over previous
//
#include <hip/hip_runtime.h>

#define N_NODES 50000
#define N_EDGES 800000
#define DIM 128
#define N_REL 86
#define BATCH 2048

#define TPAD 136              // 128+8 bf16: 272 B row stride -> 2-way bank alias (free)
#define QPAD 136

#define G_E8   391            // ceil(800000/2048), 8 edges/thread (800000 % 8 == 0)
#define G_GEMM 391            // ceil(50000/128)
#define G_TQ   172            // 86 relations x 2 d-blocks
#define NB_SCAN 49            // ceil(50000/1024)
#define RDY    0x40000000

using bf16x8 = __attribute__((ext_vector_type(8))) short;
using f32x4  = __attribute__((ext_vector_type(4))) float;

static __device__ __forceinline__ unsigned short f2bf(float f) {
  union { float f; unsigned int i; } v; v.f = f;
  unsigned int x = v.i;
  unsigned int r = x + 0x7FFFu + ((x >> 16) & 1u);
  return (unsigned short)(r >> 16);
}
static __device__ __forceinline__ float bf2f(unsigned short u) {
  union { unsigned int i; float f; } v;
  v.i = ((unsigned int)u) << 16;
  return v.f;
}

// ---------------- kernel 0: zero cnt + scan flags + weight prep ----------------

__global__ __launch_bounds__(256) void k_prep_zero(const float* __restrict__ W1, const float* __restrict__ W2,
                                                   const float* __restrict__ M,
                                                   unsigned short* __restrict__ W1th, unsigned short* __restrict__ W1tl,
                                                   unsigned short* __restrict__ W2th, unsigned short* __restrict__ W2tl,
                                                   unsigned short* __restrict__ Mth,
                                                   int* __restrict__ cnt, int* __restrict__ flags) {
  int g = blockIdx.x * 256 + threadIdx.x;          // 65536 threads
  if (g < N_NODES) cnt[g] = 0;
  if (g < 64) flags[g] = 0;
  if (g < DIM * DIM) {
    int k = g >> 7, n = g & 127;
    int t = n * DIM + k;
    float w1 = W1[g]; unsigned short h1 = f2bf(w1);
    W1th[t] = h1; W1tl[t] = f2bf(w1 - bf2f(h1));
    float w2 = W2[g]; unsigned short h2 = f2bf(w2);
    W2th[t] = h2; W2tl[t] = f2bf(w2 - bf2f(h2));
    Mth[t] = f2bf(M[g]);
  }
}

// ---------------- megaA: edge count (+epos, 8/thread)  ||  decoder TQ ----------------

__global__ __launch_bounds__(256) void k_megaA(const int* __restrict__ dst,
                                               int* __restrict__ cnt, int* __restrict__ epos,
                                               const float* __restrict__ Rel,
                                               const unsigned short* __restrict__ Mth,
                                               unsigned short* __restrict__ Qbf) {
  __shared__ __align__(16) unsigned short Ts[64 * TPAD];
  int bid = blockIdx.x;
  int wave = threadIdx.x >> 6, lane = threadIdx.x & 63;
  int l15 = lane & 15, quad = lane >> 4;
  union U { uint4 u; bf16x8 h; };

  if (bid < G_E8) {
    int i0 = bid * 2048 + threadIdx.x * 8;
    if (i0 < N_EDGES) {
      int4 da = *(const int4*)(dst + i0);
      int4 db = *(const int4*)(dst + i0 + 4);
      int4 ea, eb;
      ea.x = atomicAdd(&cnt[da.x], 1);
      ea.y = atomicAdd(&cnt[da.y], 1);
      ea.z = atomicAdd(&cnt[da.z], 1);
      ea.w = atomicAdd(&cnt[da.w], 1);
      eb.x = atomicAdd(&cnt[db.x], 1);
      eb.y = atomicAdd(&cnt[db.y], 1);
      eb.z = atomicAdd(&cnt[db.z], 1);
      eb.w = atomicAdd(&cnt[db.w], 1);
      *(int4*)(epos + i0) = ea;
      *(int4*)(epos + i0 + 4) = eb;
    }
  } else {
    // ---- decoder precompute: T_r = Rel_r @ M (LDS), Q_r = T_r @ Rel_r^T ----
    int rb = bid - G_E8;
    int r = rb >> 1, dblk = rb & 1;
    const float* Rr = Rel + (size_t)r * DIM * DIM;
    unsigned short* Qr = Qbf + (size_t)r * DIM * DIM;
    int dw = dblk * 64 + wave * 16;
    f32x4 acc[8];
    #pragma unroll
    for (int nt = 0; nt < 8; ++nt) acc[nt] = f32x4{0.f, 0.f, 0.f, 0.f};
    #pragma unroll
    for (int ks = 0; ks < 4; ++ks) {
      int k0 = ks * 32 + quad * 8;
      const float* ap = Rr + (size_t)(dw + l15) * DIM + k0;
      float av[8];
      *(float4*)(av)     = *(const float4*)(ap);
      *(float4*)(av + 4) = *(const float4*)(ap + 4);
      bf16x8 a;
      #pragma unroll
      for (int j = 0; j < 8; ++j) a[j] = (short)f2bf(av[j]);
      #pragma unroll
      for (int nt = 0; nt < 8; ++nt) {
        U b; b.u = *(const uint4*)(Mth + (nt * 16 + l15) * DIM + k0);
        acc[nt] = __builtin_amdgcn_mfma_f32_16x16x32_bf16(a, b.h, acc[nt], 0, 0, 0);
      }
    }
    #pragma unroll
    for (int nt = 0; nt < 8; ++nt)
      #pragma unroll
      for (int reg = 0; reg < 4; ++reg)
        Ts[(wave * 16 + quad * 4 + reg) * TPAD + nt * 16 + l15] = f2bf(acc[nt][reg]);
    __syncthreads();
    f32x4 qacc[8];
    #pragma unroll
    for (int nt = 0; nt < 8; ++nt) qacc[nt] = f32x4{0.f, 0.f, 0.f, 0.f};
    #pragma unroll
    for (int ks = 0; ks < 4; ++ks) {
      int k0 = ks * 32 + quad * 8;
      U a; a.u = *(const uint4*)(&Ts[(wave * 16 + l15) * TPAD + k0]);
      #pragma unroll
      for (int nt = 0; nt < 8; ++nt) {
        const float* bp = Rr + (size_t)(nt * 16 + l15) * DIM + k0;
        float bv[8];
        *(float4*)(bv)     = *(const float4*)(bp);
        *(float4*)(bv + 4) = *(const float4*)(bp + 4);
        bf16x8 b;
        #pragma unroll
        for (int j = 0; j < 8; ++j) b[j] = (short)f2bf(bv[j]);
        qacc[nt] = __builtin_amdgcn_mfma_f32_16x16x32_bf16(a.h, b, qacc[nt], 0, 0, 0);
      }
    }
    #pragma unroll
    for (int nt = 0; nt < 8; ++nt)
      #pragma unroll
      for (int reg = 0; reg < 4; ++reg)
        Qr[(size_t)(dw + quad * 4 + reg) * DIM + nt * 16 + l15] = f2bf(qacc[nt][reg]);
  }
}

// ---------------- single-dispatch chained scan: dinv + rowptr ----------------
// 49 blocks (all co-resident on 256 CUs -> spin-wait is safe). Block b publishes
// its inclusive prefix with a ready bit; block b+1 spins on it.

__global__ __launch_bounds__(256) void k_scan_one(const int* __restrict__ cnt, float* __restrict__ dinv,
                                                  int* __restrict__ rowptr, int* __restrict__ flags) {
  __shared__ int sd[256];
  __shared__ int s_prefix;
  int b = blockIdx.x;
  int base = b * 1024;
  int t = threadIdx.x;
  int v[4]; int s = 0;
  #pragma unroll
  for (int i = 0; i < 4; ++i) {
    int idx = base + t * 4 + i;
    if (idx < N_NODES) {
      int c = cnt[idx];
      v[i] = c;
      dinv[idx] = rsqrtf((float)(c + 1));
    } else v[i] = 0;
    s += v[i];
  }
  sd[t] = s; __syncthreads();
  // inclusive Hillis-Steele scan over the 256 per-thread sums
  for (int off = 1; off < 256; off <<= 1) {
    int y = (t >= off) ? sd[t - off] : 0;
    __syncthreads();
    sd[t] += y;
    __syncthreads();
  }
  int local_excl = sd[t] - s;
  int total = sd[255];
  if (t == 0) {
    int prefix = 0;
    if (b > 0) {
      int f;
      while ((((f = atomicAdd(&flags[b - 1], 0))) & RDY) == 0) { }
      prefix = f & ~RDY;
    }
    atomicExch(&flags[b], (prefix + total) | RDY);
    s_prefix = prefix;
    if (b == NB_SCAN - 1) rowptr[N_NODES] = prefix + total;
  }
  __syncthreads();
  int pre = s_prefix + local_excl;
  #pragma unroll
  for (int i = 0; i < 4; ++i) {
    int idx = base + t * 4 + i;
    if (idx < N_NODES) rowptr[idx] = pre;
    pre += v[i];
  }
}

// ---------------- megaB: CSR fill (no atomics, 8/thread)  ||  gemm1 ----------------

__global__ __launch_bounds__(256) void k_megaB(const int* __restrict__ src, const int* __restrict__ dst,
                                               const int* __restrict__ rowptr, const int* __restrict__ epos,
                                               int* __restrict__ esrc,
                                               const float* __restrict__ x,
                                               const unsigned short* __restrict__ W1th,
                                               const unsigned short* __restrict__ W1tl,
                                               unsigned short* __restrict__ hout) {
  int bid = blockIdx.x;
  union U { uint4 u; bf16x8 h; };
  if (bid < G_E8) {
    int i0 = bid * 2048 + threadIdx.x * 8;
    if (i0 < N_EDGES) {
      int4 sa = *(const int4*)(src + i0);
      int4 sb = *(const int4*)(src + i0 + 4);
      int4 da = *(const int4*)(dst + i0);
      int4 db = *(const int4*)(dst + i0 + 4);
      int4 ea = *(const int4*)(epos + i0);
      int4 eb = *(const int4*)(epos + i0 + 4);
      esrc[rowptr[da.x] + ea.x] = sa.x;
      esrc[rowptr[da.y] + ea.y] = sa.y;
      esrc[rowptr[da.z] + ea.z] = sa.z;
      esrc[rowptr[da.w] + ea.w] = sa.w;
      esrc[rowptr[db.x] + eb.x] = sb.x;
      esrc[rowptr[db.y] + eb.y] = sb.y;
      esrc[rowptr[db.z] + eb.z] = sb.z;
      esrc[rowptr[db.w] + eb.w] = sb.w;
    }
  } else {
    // ---- node GEMM layer 1: hout = x @ W1 (hi/lo 3-term, bf16 out) ----
    int wave = threadIdx.x >> 6, lane = threadIdx.x & 63;
    int l15 = lane & 15, quad = lane >> 4;
    int r0 = (bid - G_E8) * 128 + wave * 32;
    f32x4 acc[2][8];
    #pragma unroll
    for (int mt = 0; mt < 2; ++mt)
      #pragma unroll
      for (int nt = 0; nt < 8; ++nt) acc[mt][nt] = f32x4{0.f, 0.f, 0.f, 0.f};
    #pragma unroll
    for (int ks = 0; ks < 4; ++ks) {
      int k0 = ks * 32 + quad * 8;
      bf16x8 ah[2], al[2];
      #pragma unroll
      for (int mt = 0; mt < 2; ++mt) {
        int row = r0 + mt * 16 + l15;
        row = (row < N_NODES) ? row : (N_NODES - 1);
        const float* xp = x + (size_t)row * DIM + k0;
        float xv[8];
        *(float4*)(xv)     = *(const float4*)(xp);
        *(float4*)(xv + 4) = *(const float4*)(xp + 4);
        #pragma unroll
        for (int j = 0; j < 8; ++j) {
          unsigned short h = f2bf(xv[j]);
          ah[mt][j] = (short)h;
          al[mt][j] = (short)f2bf(xv[j] - bf2f(h));
        }
      }
      #pragma unroll
      for (int nt = 0; nt < 8; ++nt) {
        U bh, bl;
        bh.u = *(const uint4*)(W1th + (nt * 16 + l15) * DIM + k0);
        bl.u = *(const uint4*)(W1tl + (nt * 16 + l15) * DIM + k0);
        #pragma unroll
        for (int mt = 0; mt < 2; ++mt) {
          acc[mt][nt] = __builtin_amdgcn_mfma_f32_16x16x32_bf16(ah[mt], bh.h, acc[mt][nt], 0, 0, 0);
          acc[mt][nt] = __builtin_amdgcn_mfma_f32_16x16x32_bf16(al[mt], bh.h, acc[mt][nt], 0, 0, 0);
          acc[mt][nt] = __builtin_amdgcn_mfma_f32_16x16x32_bf16(ah[mt], bl.h, acc[mt][nt], 0, 0, 0);
        }
      }
    }
    #pragma unroll
    for (int mt = 0; mt < 2; ++mt)
      #pragma unroll
      for (int reg = 0; reg < 4; ++reg) {
        int row = r0 + mt * 16 + quad * 4 + reg;
        if (row < N_NODES) {
          #pragma unroll
          for (int nt = 0; nt < 8; ++nt)
            hout[(size_t)row * DIM + nt * 16 + l15] = f2bf(acc[mt][nt][reg]);
        }
      }
  }
}

// ---------------- agg: bf16 plane in -> hi/lo bf16 planes out ----------------

__global__ __launch_bounds__(256) void k_agg_hl(const unsigned short* __restrict__ h,
                                                const int* __restrict__ rowptr,
                                                const int* __restrict__ esrc, const float* __restrict__ dinv,
                                                const float* __restrict__ bias,
                                                unsigned short* __restrict__ outh,
                                                unsigned short* __restrict__ outl) {
  int node = blockIdx.x * 8 + (threadIdx.x >> 5);
  if (node >= N_NODES) return;
  int lane = threadIdx.x & 31;
  const ushort4* h4 = (const ushort4*)h;
  float di = dinv[node];
  ushort4 hv = h4[(size_t)node * 32 + lane];
  float ax = di * bf2f(hv.x), ay = di * bf2f(hv.y), az = di * bf2f(hv.z), aw = di * bf2f(hv.w);
  int e = rowptr[node], end = rowptr[node + 1];
  for (; e + 3 < end; e += 4) {
    int s0 = esrc[e], s1 = esrc[e + 1], s2 = esrc[e + 2], s3 = esrc[e + 3];
    float d0 = dinv[s0], d1 = dinv[s1], d2 = dinv[s2], d3 = dinv[s3];
    ushort4 v0 = h4[(size_t)s0 * 32 + lane];
    ushort4 v1 = h4[(size_t)s1 * 32 + lane];
    ushort4 v2 = h4[(size_t)s2 * 32 + lane];
    ushort4 v3 = h4[(size_t)s3 * 32 + lane];
    ax = fmaf(d0, bf2f(v0.x), ax); ay = fmaf(d0, bf2f(v0.y), ay); az = fmaf(d0, bf2f(v0.z), az); aw = fmaf(d0, bf2f(v0.w), aw);
    ax = fmaf(d1, bf2f(v1.x), ax); ay = fmaf(d1, bf2f(v1.y), ay); az = fmaf(d1, bf2f(v1.z), az); aw = fmaf(d1, bf2f(v1.w), aw);
    ax = fmaf(d2, bf2f(v2.x), ax); ay = fmaf(d2, bf2f(v2.y), ay); az = fmaf(d2, bf2f(v2.z), az); aw = fmaf(d2, bf2f(v2.w), aw);
    ax = fmaf(d3, bf2f(v3.x), ax); ay = fmaf(d3, bf2f(v3.y), ay); az = fmaf(d3, bf2f(v3.z), az); aw = fmaf(d3, bf2f(v3.w), aw);
  }
  for (; e < end; ++e) {
    int s = esrc[e];
    float ds = dinv[s];
    ushort4 vs = h4[(size_t)s * 32 + lane];
    ax = fmaf(ds, bf2f(vs.x), ax); ay = fmaf(ds, bf2f(vs.y), ay);
    az = fmaf(ds, bf2f(vs.z), az); aw = fmaf(ds, bf2f(vs.w), aw);
  }
  float4 bb = ((const float4*)bias)[lane];
  float vx = fmaf(di, ax, bb.x), vy = fmaf(di, ay, bb.y);
  float vz = fmaf(di, az, bb.z), vw = fmaf(di, aw, bb.w);
  ushort4 hi4, lo4;
  hi4.x = f2bf(vx); lo4.x = f2bf(vx - bf2f(hi4.x));
  hi4.y = f2bf(vy); lo4.y = f2bf(vy - bf2f(hi4.y));
  hi4.z = f2bf(vz); lo4.z = f2bf(vz - bf2f(hi4.z));
  hi4.w = f2bf(vw); lo4.w = f2bf(vw - bf2f(hi4.w));
  ((ushort4*)outh)[(size_t)node * 32 + lane] = hi4;
  ((ushort4*)outl)[(size_t)node * 32 + lane] = lo4;
}

// ---------------- gemm2: A from hi/lo planes, 3-term, bf16 out ----------------

__global__ __launch_bounds__(256) void k_gemm_hl(const unsigned short* __restrict__ xh,
                                                 const unsigned short* __restrict__ xl,
                                                 const unsigned short* __restrict__ Wth,
                                                 const unsigned short* __restrict__ Wtl,
                                                 unsigned short* __restrict__ out, int nrows) {
  int wave = threadIdx.x >> 6, lane = threadIdx.x & 63;
  int l15 = lane & 15, quad = lane >> 4;
  int r0 = blockIdx.x * 128 + wave * 32;
  f32x4 acc[2][8];
  #pragma unroll
  for (int mt = 0; mt < 2; ++mt)
    #pragma unroll
    for (int nt = 0; nt < 8; ++nt) acc[mt][nt] = f32x4{0.f, 0.f, 0.f, 0.f};
  union U { uint4 u; bf16x8 h; };
  #pragma unroll
  for (int ks = 0; ks < 4; ++ks) {
    int k0 = ks * 32 + quad * 8;
    U ah[2], al[2];
    #pragma unroll
    for (int mt = 0; mt < 2; ++mt) {
      int row = r0 + mt * 16 + l15;
      row = (row < nrows) ? row : (nrows - 1);
      ah[mt].u = *(const uint4*)(xh + (size_t)row * DIM + k0);
      al[mt].u = *(const uint4*)(xl + (size_t)row * DIM + k0);
    }
    #pragma unroll
    for (int nt = 0; nt < 8; ++nt) {
      U bh, bl;
      bh.u = *(const uint4*)(Wth + (nt * 16 + l15) * DIM + k0);
      bl.u = *(const uint4*)(Wtl + (nt * 16 + l15) * DIM + k0);
      #pragma unroll
      for (int mt = 0; mt < 2; ++mt) {
        acc[mt][nt] = __builtin_amdgcn_mfma_f32_16x16x32_bf16(ah[mt].h, bh.h, acc[mt][nt], 0, 0, 0);
        acc[mt][nt] = __builtin_amdgcn_mfma_f32_16x16x32_bf16(al[mt].h, bh.h, acc[mt][nt], 0, 0, 0);
        acc[mt][nt] = __builtin_amdgcn_mfma_f32_16x16x32_bf16(ah[mt].h, bl.h, acc[mt][nt], 0, 0, 0);
      }
    }
  }
  #pragma unroll
  for (int mt = 0; mt < 2; ++mt)
    #pragma unroll
    for (int reg = 0; reg < 4; ++reg) {
      int row = r0 + mt * 16 + quad * 4 + reg;
      if (row < nrows) {
        #pragma unroll
        for (int nt = 0; nt < 8; ++nt)
          out[(size_t)row * DIM + nt * 16 + l15] = f2bf(acc[mt][nt][reg]);
      }
    }
}

// ---------------- predict via MFMA, inline gather from hi/lo planes ----------------

__global__ __launch_bounds__(256) void k_predict_mfma(const unsigned short* __restrict__ xh,
                                                      const unsigned short* __restrict__ xl,
                                                      const int* __restrict__ head,
                                                      const int* __restrict__ tail,
                                                      const unsigned short* __restrict__ Qbf,
                                                      float* __restrict__ out) {
  __shared__ __align__(16) unsigned short Qs[DIM * QPAD];
  __shared__ int Hidx[128];
  __shared__ int Tidx[128];
  int r = blockIdx.y;
  const unsigned short* Qr = Qbf + (size_t)r * DIM * DIM;
  for (int i = threadIdx.x; i < DIM * DIM / 8; i += 256) {
    int d = i >> 4, c = (i & 15) * 8;
    uint4 v = ((const uint4*)Qr)[i];
    *(uint4*)(&Qs[d * QPAD + c]) = v;
  }
  if (threadIdx.x < 128) Hidx[threadIdx.x] = head[blockIdx.x * 128 + threadIdx.x];
  else Tidx[threadIdx.x - 128] = tail[blockIdx.x * 128 + threadIdx.x - 128];
  __syncthreads();
  int wave = threadIdx.x >> 6, lane = threadIdx.x & 63;
  int l15 = lane & 15, quad = lane >> 4;
  int t0r = Tidx[wave * 32 + l15];
  int t1r = Tidx[wave * 32 + 16 + l15];

  f32x4 acc[2][8];
  #pragma unroll
  for (int m = 0; m < 2; ++m)
    #pragma unroll
    for (int n = 0; n < 8; ++n) acc[m][n] = f32x4{0.f, 0.f, 0.f, 0.f};

  union U { uint4 u; bf16x8 h; };
  #pragma unroll
  for (int ks = 0; ks < 4; ++ks) {
    int eoff = ks * 32 + quad * 8;
    U a0, a1;
    a0.u = *(const uint4*)(xh + (size_t)t0r * DIM + eoff);   // tail = hi plane
    a1.u = *(const uint4*)(xh + (size_t)t1r * DIM + eoff);
    #pragma unroll
    for (int nt = 0; nt < 8; ++nt) {
      U b; b.u = *(const uint4*)(&Qs[(nt * 16 + l15) * QPAD + eoff]);
      acc[0][nt] = __builtin_amdgcn_mfma_f32_16x16x32_bf16(a0.h, b.h, acc[0][nt], 0, 0, 0);
      acc[1][nt] = __builtin_amdgcn_mfma_f32_16x16x32_bf16(a1.h, b.h, acc[1][nt], 0, 0, 0);
    }
  }

  int bbase = blockIdx.x * 128 + wave * 32;
  #pragma unroll
  for (int m = 0; m < 2; ++m) {
    #pragma unroll
    for (int reg = 0; reg < 4; ++reg) {
      int bl = wave * 32 + m * 16 + quad * 4 + reg;
      int hrow = Hidx[bl];
      float s = 0.f;
      #pragma unroll
      for (int nt = 0; nt < 8; ++nt) {
        size_t idx = (size_t)hrow * DIM + nt * 16 + l15;
        s += (bf2f(xh[idx]) + bf2f(xl[idx])) * acc[m][nt][reg];  // head = hi+lo
      }
      #pragma unroll
      for (int off = 1; off < 16; off <<= 1) s += __shfl_xor(s, off, 64);
      if (l15 == 0) out[(size_t)(bbase + m * 16 + quad * 4 + reg) * N_REL + r] = s;
    }
  }
}

// ---------------- launch ----------------

extern "C" void kernel_launch(void* const* d_in, const int* in_sizes, int n_in,
                              void* d_out, int out_size, void* d_ws, size_t ws_size,
                              hipStream_t stream) {
  (void)in_sizes; (void)n_in; (void)out_size; (void)ws_size;
  const float* init_emb = (const float*)d_in[0];
  const float* W1  = (const float*)d_in[1];
  const float* b1  = (const float*)d_in[2];
  const float* W2  = (const float*)d_in[3];
  const float* b2  = (const float*)d_in[4];
  const float* Rel = (const float*)d_in[5];
  const float* M   = (const float*)d_in[6];
  const int* head  = (const int*)d_in[7];
  const int* tail  = (const int*)d_in[8];
  const int* src   = (const int*)d_in[9];
  const int* dst   = src + N_EDGES;
  float* out = (float*)d_out;

  char* p = (char*)d_ws;
  auto alloc = [&](size_t bytes) { char* q = p; p += (bytes + 511) & ~(size_t)511; return q; };
  int*   cnt    = (int*)alloc((size_t)N_NODES * 4);
  int*   rowptr = (int*)alloc((size_t)(N_NODES + 1) * 4);
  int*   flags  = (int*)alloc(64 * 4);
  int*   esrc   = (int*)alloc((size_t)N_EDGES * 4);
  int*   epos   = (int*)alloc((size_t)N_EDGES * 4);
  float* dinv   = (float*)alloc((size_t)N_NODES * 4);
  unsigned short* hbuf1 = (unsigned short*)alloc((size_t)N_NODES * DIM * 2);
  unsigned short* aggh  = (unsigned short*)alloc((size_t)N_NODES * DIM * 2);
  unsigned short* aggl  = (unsigned short*)alloc((size_t)N_NODES * DIM * 2);
  unsigned short* hbuf2 = (unsigned short*)alloc((size_t)N_NODES * DIM * 2);
  unsigned short* xh    = (unsigned short*)alloc((size_t)N_NODES * DIM * 2);
  unsigned short* xl    = (unsigned short*)alloc((size_t)N_NODES * DIM * 2);
  unsigned short* Qbf   = (unsigned short*)alloc((size_t)N_REL * DIM * DIM * 2);
  unsigned short* W1th  = (unsigned short*)alloc((size_t)DIM * DIM * 2);
  unsigned short* W1tl  = (unsigned short*)alloc((size_t)DIM * DIM * 2);
  unsigned short* W2th  = (unsigned short*)alloc((size_t)DIM * DIM * 2);
  unsigned short* W2tl  = (unsigned short*)alloc((size_t)DIM * DIM * 2);
  unsigned short* Mth   = (unsigned short*)alloc((size_t)DIM * DIM * 2);

  // 1: zero cnt/flags + weight prep
  k_prep_zero<<<256, 256, 0, stream>>>(W1, W2, M, W1th, W1tl, W2th, W2tl, Mth, cnt, flags);
  // 2: count(+epos, 8/thr) || decoder TQ
  k_megaA<<<G_E8 + G_TQ, 256, 0, stream>>>(dst, cnt, epos, Rel, Mth, Qbf);
  // 3: single-dispatch chained scan (dinv + rowptr)
  k_scan_one<<<NB_SCAN, 256, 0, stream>>>(cnt, dinv, rowptr, flags);
  // 4: fill (no atomics, 8/thr) || gemm1
  k_megaB<<<G_E8 + G_GEMM, 256, 0, stream>>>(src, dst, rowptr, epos, esrc,
                                             init_emb, W1th, W1tl, hbuf1);
  // 5: agg1 -> hi/lo planes
  k_agg_hl<<<(N_NODES + 7) / 8, 256, 0, stream>>>(hbuf1, rowptr, esrc, dinv, b1, aggh, aggl);
  // 6: gemm2 from planes
  k_gemm_hl<<<(N_NODES + 127) / 128, 256, 0, stream>>>(aggh, aggl, W2th, W2tl, hbuf2, N_NODES);
  // 7: agg2 -> hi/lo planes
  k_agg_hl<<<(N_NODES + 7) / 8, 256, 0, stream>>>(hbuf2, rowptr, esrc, dinv, b2, xh, xl);
  // 8: predict (inline gather from planes)
  k_predict_mfma<<<dim3(BATCH / 128, N_REL), 256, 0, stream>>>(xh, xl, head, tail, Qbf, out);
}